// Round 18
// baseline (224.568 us; speedup 1.0000x reference)
//
#include <hip/hip_runtime.h>
#include <hip/hip_bf16.h>
#include <math.h>

// Fused QKV(+bias) -> RoPE -> 4-head causal attention -> FC2(+bias) -> SiLU
// B=2048, L=119, D=128, H=4, HD=32. fp32 in/out, bf16 MFMA internally.
// Head split: model channel c = d*4 + h. Head merge: out channel c' = h*32 + d.
//
// Round 17: pure waves-per-SIMD A/B on the R16 winner (217.6us). R16 counters:
// VGPR 88 (128-class, 16 waves/CU allowed) but LDS caps at 1 block/CU and the
// block has only 8 waves -> 2 waves/SIMD. The per-wave dependent chains
// (ds_read ~120cy, L2 ~300cy, shfl/exp) have nothing to overlap with. This
// round: SAME block-per-batch, SAME LDS, SAME inner code bodies, but 1024 thr
// = 16 waves with per-wave job lists halved:
//   QKV: wave -> (mt=wv&3, head=wv>>2): q,k pair + v (3 tiles, was 6).
//   attention: wave -> ONE task (h=wv>>2, qt=wv&3) (was 2).
//   FC2: wave -> (mrow=wv&7, nhalf=wv>>3): 4 nt (was 8).
// Work/LDS/register-class unchanged; waves/SIMD 2 -> 4.
// Layouts (m74/m101): 32x32 C/D col=lane&31, row=(reg&3)+8*(reg>>2)+4*(lane>>5).
// A: row=lane&31, k=(lane>>5)*8+j. B: col=lane&31, same k.
// LDS: qs/ksm [4][128][40] 2x40,960 + vT [4][32][128] 32,768 + tabL [119][65]
// 30,940 = 145,628 B.

#define L_SEQ 119
#define D_MODEL 128
#define SCALE 0.17677669529663687f  // 1/sqrt(32)
#define NEGINF -1e30f

typedef __bf16 bf16x8 __attribute__((ext_vector_type(8)));
typedef __bf16 bf16x2 __attribute__((ext_vector_type(2)));
typedef float f32x4 __attribute__((ext_vector_type(4)));
typedef float f32x16 __attribute__((ext_vector_type(16)));

// ---- single prep kernel: RoPE table + Wb A-frags + bb2 + Wfc2 B-frags ----
__global__ void prep_kernel(const float* __restrict__ Wqkv,
                            const float* __restrict__ bqkv,
                            const float* __restrict__ Wfc2,
                            unsigned* __restrict__ tabu,
                            __bf16* __restrict__ Wb, float* __restrict__ bb2,
                            __bf16* __restrict__ Wf2b) {
  int i = blockIdx.x * 256 + threadIdx.x;  // 0..49151
  {  // Wb (all threads)
    int j = i & 7, lane = (i >> 3) & 63, ks = (i >> 9) & 7, nt = i >> 12;
    int d = lane & 31;
    int h = nt / 3, qkv = nt % 3;
    int k = ks * 16 + (lane >> 5) * 8 + j;
    Wb[i] = (__bf16)Wqkv[(qkv * 128 + d * 4 + h) * 128 + k];
  }
  if (i < 384) {  // bb2
    int nt2 = i >> 5, dd = i & 31;
    bb2[i] = bqkv[(nt2 % 3) * 128 + dd * 4 + (nt2 / 3)];
  }
  if (i < 16384) {  // Wf2b
    int j = i & 7, lane = (i >> 3) & 63, kb = (i >> 9) & 3, nt = i >> 11;
    int n = nt * 16 + (lane & 15);
    int k = kb * 32 + (lane >> 4) * 8 + j;
    Wf2b[i] = (__bf16)Wfc2[n * 128 + k];
  }
  if (i < L_SEQ * 64) {  // RoPE table (bf16-rounded, as reference)
    int l = i >> 6, j = i & 63;
    float inv = 1.0f / powf(10000.0f, (float)(2 * j) / 128.0f);
    float f = (float)l * inv;
    union { bf16x2 v; unsigned u; } cs;
    cs.v[0] = (__bf16)cosf(f);
    cs.v[1] = (__bf16)sinf(f);
    tabu[i] = cs.u;
  }
}

__global__ __launch_bounds__(1024) void fused_all(
    const float* __restrict__ x, const __bf16* __restrict__ Wb,
    const float* __restrict__ bb2, const unsigned* __restrict__ tabu,
    const __bf16* __restrict__ Wf2b, const float* __restrict__ bfc2,
    float* __restrict__ out) {
  __shared__ __align__(16) __bf16 qs[4 * 128 * 40];   // 40,960 B
  __shared__ __align__(16) __bf16 ksm[4 * 128 * 40];  // 40,960 B
  __shared__ __align__(16) __bf16 vT[4 * 32 * 128];   // 32,768 B (XOR-swizzled)
  __shared__ unsigned tabL[L_SEQ * 65];               // 30,940 B

  const int t = threadIdx.x, b = blockIdx.x;
  const int lane = t & 63, wv = t >> 6;  // wv in 0..15
  const int ln31 = lane & 31, hi = lane >> 5;

  // ---- stage RoPE table (stride 65 words -> conflict-free lane-l reads)
  for (int i = t; i < L_SEQ * 64; i += 1024)
    tabL[(i >> 6) * 65 + (i & 63)] = tabu[i];
  // ---- zero vT tail cols 119..127
  for (int i = t; i < 4 * 32 * 9; i += 1024) {
    int hd = i / 9, cc = L_SEQ + i % 9, d = hd & 31;
    vT[hd * 128 + (cc ^ ((d & 7) << 3))] = (__bf16)0.0f;
  }
  __syncthreads();

  // ======== QKV: wave -> (Mtile = wv&3, head = wv>>2): q,k pair + v ========
  const int mt = wv & 3, hd = wv >> 2;
  const int l_me = mt * 32 + ln31;  // this lane's sequence row (col of C)
  const bool live = (l_me < L_SEQ);
  {
    int xr = live ? l_me : (L_SEQ - 1);
    const float* xrow = x + ((size_t)b * L_SEQ + xr) * 128;
    bf16x8 af[8];
#pragma unroll
    for (int ks = 0; ks < 8; ++ks) {
      float4 lo = *(const float4*)&xrow[ks * 16 + hi * 8];
      float4 hi4 = *(const float4*)&xrow[ks * 16 + hi * 8 + 4];
      bf16x8 v;
      v[0] = (__bf16)lo.x; v[1] = (__bf16)lo.y; v[2] = (__bf16)lo.z; v[3] = (__bf16)lo.w;
      v[4] = (__bf16)hi4.x; v[5] = (__bf16)hi4.y; v[6] = (__bf16)hi4.z; v[7] = (__bf16)hi4.w;
      af[ks] = v;
    }
    const int ntq = hd * 3;  // q tile; +1 = k; +2 = v
    // ---- q,k pair (both RoPE)
    {
      f32x16 a0 = {}, a1 = {};
#pragma unroll
      for (int ks = 0; ks < 8; ++ks) {
        bf16x8 wf0 = *(const bf16x8*)&Wb[(((ntq * 8 + ks) * 64) + lane) * 8];
        bf16x8 wf1 = *(const bf16x8*)&Wb[((((ntq + 1) * 8 + ks) * 64) + lane) * 8];
        a0 = __builtin_amdgcn_mfma_f32_32x32x16_bf16(wf0, af[ks], a0, 0, 0, 0);
        a1 = __builtin_amdgcn_mfma_f32_32x32x16_bf16(wf1, af[ks], a1, 0, 0, 0);
      }
#pragma unroll
      for (int e = 0; e < 2; ++e) {
        const f32x16& A = e ? a1 : a0;
        const int nt = ntq + e;
        __bf16* base = e ? ksm : qs;
        if (live) {
#pragma unroll
          for (int rg = 0; rg < 8; ++rg) {
            const int c_lo = (rg & 3) + 8 * (rg >> 2);
            int d = c_lo + 4 * hi;  // 0..15
            union { bf16x2 v; unsigned u; } cs;
            cs.u = tabL[l_me * 65 + 4 * d + hd];
            float c = (float)cs.v[0], s = (float)cs.v[1];
            float v1 = A[rg] + bb2[nt * 32 + d];
            float v2 = A[rg + 8] + bb2[nt * 32 + d + 16];
            if (e == 0) { v1 *= SCALE; v2 *= SCALE; }
            union { bf16x2 v; unsigned u; } pk;
            pk.v[0] = (__bf16)(v1 * c + v2 * s);
            pk.v[1] = (__bf16)(v2 * c - v1 * s);
            *(unsigned*)&base[(hd * 128 + l_me) * 40 + 2 * d] = pk.u;
          }
        }
      }
    }
    // ---- v tile
    {
      f32x16 a2 = {};
#pragma unroll
      for (int ks = 0; ks < 8; ++ks) {
        bf16x8 wf2 = *(const bf16x8*)&Wb[((((ntq + 2) * 8 + ks) * 64) + lane) * 8];
        a2 = __builtin_amdgcn_mfma_f32_32x32x16_bf16(wf2, af[ks], a2, 0, 0, 0);
      }
      if (live) {
#pragma unroll
        for (int rg = 0; rg < 16; ++rg) {
          const int d = (rg & 3) + 8 * (rg >> 2) + 4 * hi;  // 0..31
          float val = a2[rg] + bb2[(ntq + 2) * 32 + d];
          vT[(hd * 32 + d) * 128 + (l_me ^ ((d & 7) << 3))] = (__bf16)val;
        }
      }
    }
  }
  __syncthreads();

  // ======== attention: wave -> ONE task (h = wv>>2, qt = wv&3) ========
  {
    const int h = wv >> 2, qt = wv & 3;  // runtime wave-uniform qt (R13-clean)
    bf16x8 qf0 = *(const bf16x8*)&qs[(h * 128 + qt * 32 + ln31) * 40 + hi * 8];
    bf16x8 qf1 = *(const bf16x8*)&qs[(h * 128 + qt * 32 + ln31) * 40 + 16 + hi * 8];
    f32x16 s[4];
#pragma unroll
    for (int kt = 0; kt < 4; ++kt) {
      if (kt <= qt) {
        bf16x8 kf0 = *(const bf16x8*)&ksm[(h * 128 + kt * 32 + ln31) * 40 + hi * 8];
        bf16x8 kf1 = *(const bf16x8*)&ksm[(h * 128 + kt * 32 + ln31) * 40 + 16 + hi * 8];
        f32x16 z = {};
        z = __builtin_amdgcn_mfma_f32_32x32x16_bf16(kf0, qf0, z, 0, 0, 0);
        s[kt] = __builtin_amdgcn_mfma_f32_32x32x16_bf16(kf1, qf1, z, 0, 0, 0);
        if (kt == qt) {  // diagonal mask; s[] index compile-time (rule #20)
#pragma unroll
          for (int rg = 0; rg < 16; ++rg) {
            const int c_lo = (rg & 3) + 8 * (rg >> 2);
            int crow = c_lo + 4 * hi;
            s[kt][rg] = (crow <= ln31) ? s[kt][rg] : NEGINF;
          }
        }
      }
    }
    float mx = NEGINF;
#pragma unroll
    for (int kt = 0; kt < 4; ++kt)
      if (kt <= qt)
#pragma unroll
        for (int rg = 0; rg < 16; ++rg) mx = fmaxf(mx, s[kt][rg]);
    mx = fmaxf(mx, __shfl_xor(mx, 32));
    float sum = 0.0f;
#pragma unroll
    for (int kt = 0; kt < 4; ++kt)
      if (kt <= qt)
#pragma unroll
        for (int rg = 0; rg < 16; ++rg) {
          s[kt][rg] = __expf(s[kt][rg] - mx);
          sum += s[kt][rg];
        }
    sum += __shfl_xor(sum, 32);
    float inv = 1.0f / sum;
    unsigned pk[4][8];
#pragma unroll
    for (int kt = 0; kt < 4; ++kt) {
      if (kt <= qt) {
#pragma unroll
        for (int p = 0; p < 8; ++p) {
          union { bf16x2 v; unsigned u; } w;
          w.v[0] = (__bf16)(s[kt][2 * p] * inv);
          w.v[1] = (__bf16)(s[kt][2 * p + 1] * inv);
          pk[kt][p] = w.u;
        }
      }
    }
    f32x16 o = {};
#pragma unroll
    for (int kt = 0; kt < 4; ++kt) {
      if (kt <= qt) {
#pragma unroll
        for (int m = 0; m < 2; ++m) {
          unsigned f0 = (unsigned)__shfl_xor((int)pk[kt][4 * m + 0], 32);
          unsigned f1 = (unsigned)__shfl_xor((int)pk[kt][4 * m + 1], 32);
          unsigned f2 = (unsigned)__shfl_xor((int)pk[kt][4 * m + 2], 32);
          unsigned f3 = (unsigned)__shfl_xor((int)pk[kt][4 * m + 3], 32);
          union { unsigned w[4]; bf16x8 v; } Aw;
          Aw.w[0] = hi ? f2 : pk[kt][4 * m + 0];
          Aw.w[1] = hi ? f3 : pk[kt][4 * m + 1];
          Aw.w[2] = hi ? pk[kt][4 * m + 2] : f0;
          Aw.w[3] = hi ? pk[kt][4 * m + 3] : f1;
          bf16x8 vf = *(const bf16x8*)&vT[(h * 32 + ln31) * 128 +
              ((kt * 32 + m * 16 + hi * 8) ^ ((ln31 & 7) << 3))];
          o = __builtin_amdgcn_mfma_f32_32x32x16_bf16(Aw.v, vf, o, 0, 0, 0);
        }
      }
    }
#pragma unroll
    for (int rg = 0; rg < 16; ++rg) {
      const int c_lo = (rg & 3) + 8 * (rg >> 2);
      int l = qt * 32 + c_lo + 4 * hi;
      if (l < L_SEQ)
        out[((size_t)b * L_SEQ + l) * 128 + h * 32 + ln31] = o[rg];
    }
  }

  // ======== FC2 + bias + SiLU: wave -> (mrow = wv&7, nhalf = wv>>3) ========
  __syncthreads();
  {
    const int ln15 = lane & 15, kg = lane >> 4;
    const int mrow = wv & 7, nh = wv >> 3;  // 8 row-tiles x 2 col-halves
    int yr = mrow * 16 + ln15;
    if (yr > L_SEQ - 1) yr = L_SEQ - 1;
    const float* yrow = out + ((size_t)b * L_SEQ + yr) * 128;
    bf16x8 af2[4];
#pragma unroll
    for (int kb = 0; kb < 4; ++kb) {
      float4 lo = *(const float4*)&yrow[kb * 32 + kg * 8];
      float4 hi4 = *(const float4*)&yrow[kb * 32 + kg * 8 + 4];
      bf16x8 v;
      v[0] = (__bf16)lo.x; v[1] = (__bf16)lo.y; v[2] = (__bf16)lo.z; v[3] = (__bf16)lo.w;
      v[4] = (__bf16)hi4.x; v[5] = (__bf16)hi4.y; v[6] = (__bf16)hi4.z; v[7] = (__bf16)hi4.w;
      af2[kb] = v;
    }
    float bc[4];
#pragma unroll
    for (int p = 0; p < 4; ++p) bc[p] = bfc2[(nh * 4 + p) * 16 + ln15];
    f32x4 acc2[4] = {};
#pragma unroll
    for (int p = 0; p < 4; ++p)
#pragma unroll
      for (int kb = 0; kb < 4; ++kb)
        acc2[p] = __builtin_amdgcn_mfma_f32_16x16x32_bf16(
            af2[kb],
            *(const bf16x8*)&Wf2b[((((nh * 4 + p) * 4 + kb) * 64) + lane) * 8],
            acc2[p], 0, 0, 0);
#pragma unroll
    for (int p = 0; p < 4; ++p)
#pragma unroll
      for (int r = 0; r < 4; ++r) {
        int row = mrow * 16 + kg * 4 + r, c = (nh * 4 + p) * 16 + ln15;
        if (row < L_SEQ) {
          float vv = acc2[p][r] + bc[p];
          out[((size_t)b * L_SEQ + row) * 128 + c] = vv / (1.0f + __expf(-vv));
        }
      }
  }
}

extern "C" void kernel_launch(void* const* d_in, const int* in_sizes, int n_in,
                              void* d_out, int out_size, void* d_ws,
                              size_t ws_size, hipStream_t stream) {
  const float* x = (const float*)d_in[0];
  const float* Wqkv = (const float*)d_in[1];
  const float* bqkv = (const float*)d_in[2];
  const float* Wfc2 = (const float*)d_in[3];
  const float* bfc2 = (const float*)d_in[4];
  float* out = (float*)d_out;

  char* ws = (char*)d_ws;
  unsigned* tabu = (unsigned*)ws;                        // 30,464 B (pad 30,720)
  __bf16* Wb = (__bf16*)(ws + 30720);                    // 98,304 B
  float* bb2 = (float*)(ws + 30720 + 98304);             //  1,536 B
  __bf16* Wf2b = (__bf16*)(ws + 30720 + 98304 + 1536);   // 32,768 B (end 163,328)

  const int B = in_sizes[0] / (L_SEQ * D_MODEL);  // 2048
  prep_kernel<<<192, 256, 0, stream>>>(Wqkv, bqkv, Wfc2, tabu, Wb, bb2, Wf2b);
  fused_all<<<B, 1024, 0, stream>>>(x, Wb, bb2, tabu, Wf2b, bfc2, out);
}

// Round 19
// 203.860 us; speedup vs baseline: 1.1016x; 1.1016x over previous
//
#include <hip/hip_runtime.h>
#include <hip/hip_bf16.h>
#include <math.h>

// Fused QKV(+bias) -> RoPE -> 4-head causal attention -> FC2(+bias) -> SiLU
// B=2048, L=119, D=128, H=4, HD=32. fp32 in/out, bf16 MFMA internally.
// Head split: model channel c = d*4 + h. Head merge: out channel c' = h*32 + d.
//
// Round 18: R16 base (best verified, 217.6us) + y kept on-CU across the
// attention->FC2 boundary. R17's clean A/B (waves/SIMD 2->4, same work: dur
// FLAT) proved the block runs as a barrier-synced CONVOY: phase time = phase
// chain latency, wave count irrelevant. So shorten the chains: y previously
// went regs -> global -> vmcnt drain -> 16 global loads + 64 cvts (FC2 lead-in
// convoy). Now: after all qs reads (one added mid-attention barrier), the dead
// qs buffer is aliased as yL[128][136] bf16; attention writes o there
// (ds_write_b16); FC2 reads af2 via 4x ds_read_b128 (~120cy, no cvts); out is
// written exactly once. Row stride 136 elem = 272B: 16B-aligned, bank advance
// 4 -> <=2-way. Both tasks' qf pairs preloaded before the alias barrier
// (static select under unrolled ts loop).
// Layouts (m74/m101): 32x32 C/D col=lane&31, row=(reg&3)+8*(reg>>2)+4*(lane>>5).
// A: row=lane&31, k=(lane>>5)*8+j. B: col=lane&31, same k.
// LDS: qs(=yL)/ksm [4][128][40] 2x40,960 + vT 32,768 + tabL 30,940 = 145,628 B.

#define L_SEQ 119
#define D_MODEL 128
#define SCALE 0.17677669529663687f  // 1/sqrt(32)
#define NEGINF -1e30f

typedef __bf16 bf16x8 __attribute__((ext_vector_type(8)));
typedef __bf16 bf16x2 __attribute__((ext_vector_type(2)));
typedef float f32x4 __attribute__((ext_vector_type(4)));
typedef float f32x16 __attribute__((ext_vector_type(16)));

// ---- single prep kernel: RoPE table + Wb A-frags + bb2 + Wfc2 B-frags ----
__global__ void prep_kernel(const float* __restrict__ Wqkv,
                            const float* __restrict__ bqkv,
                            const float* __restrict__ Wfc2,
                            unsigned* __restrict__ tabu,
                            __bf16* __restrict__ Wb, float* __restrict__ bb2,
                            __bf16* __restrict__ Wf2b) {
  int i = blockIdx.x * 256 + threadIdx.x;  // 0..49151
  {  // Wb (all threads)
    int j = i & 7, lane = (i >> 3) & 63, ks = (i >> 9) & 7, nt = i >> 12;
    int d = lane & 31;
    int h = nt / 3, qkv = nt % 3;
    int k = ks * 16 + (lane >> 5) * 8 + j;
    Wb[i] = (__bf16)Wqkv[(qkv * 128 + d * 4 + h) * 128 + k];
  }
  if (i < 384) {  // bb2
    int nt2 = i >> 5, dd = i & 31;
    bb2[i] = bqkv[(nt2 % 3) * 128 + dd * 4 + (nt2 / 3)];
  }
  if (i < 16384) {  // Wf2b
    int j = i & 7, lane = (i >> 3) & 63, kb = (i >> 9) & 3, nt = i >> 11;
    int n = nt * 16 + (lane & 15);
    int k = kb * 32 + (lane >> 4) * 8 + j;
    Wf2b[i] = (__bf16)Wfc2[n * 128 + k];
  }
  if (i < L_SEQ * 64) {  // RoPE table (bf16-rounded, as reference)
    int l = i >> 6, j = i & 63;
    float inv = 1.0f / powf(10000.0f, (float)(2 * j) / 128.0f);
    float f = (float)l * inv;
    union { bf16x2 v; unsigned u; } cs;
    cs.v[0] = (__bf16)cosf(f);
    cs.v[1] = (__bf16)sinf(f);
    tabu[i] = cs.u;
  }
}

__global__ __launch_bounds__(512) void fused_all(
    const float* __restrict__ x, const __bf16* __restrict__ Wb,
    const float* __restrict__ bb2, const unsigned* __restrict__ tabu,
    const __bf16* __restrict__ Wf2b, const float* __restrict__ bfc2,
    float* __restrict__ out) {
  __shared__ __align__(16) __bf16 qs[4 * 128 * 40];   // 40,960 B (aliased as yL later)
  __shared__ __align__(16) __bf16 ksm[4 * 128 * 40];  // 40,960 B
  __shared__ __align__(16) __bf16 vT[4 * 32 * 128];   // 32,768 B (XOR-swizzled)
  __shared__ unsigned tabL[L_SEQ * 65];               // 30,940 B

  const int t = threadIdx.x, b = blockIdx.x;
  const int lane = t & 63, wv = t >> 6;
  const int ln31 = lane & 31, hi = lane >> 5;

  // ---- stage RoPE table (stride 65 words -> conflict-free lane-l reads)
  for (int i = t; i < L_SEQ * 64; i += 512)
    tabL[(i >> 6) * 65 + (i & 63)] = tabu[i];
  // ---- zero vT tail cols 119..127
  for (int i = t; i < 4 * 32 * 9; i += 512) {
    int hd = i / 9, cc = L_SEQ + i % 9, d = hd & 31;
    vT[hd * 128 + (cc ^ ((d & 7) << 3))] = (__bf16)0.0f;
  }
  __syncthreads();

  // ======== QKV: wave -> Mtile (wv&3), Ntile-group (wv>>2)*6 .. +5 ========
  const int mt = wv & 3, g2 = wv >> 2;
  const int l_me = mt * 32 + ln31;  // this lane's sequence row (col of C)
  const bool live = (l_me < L_SEQ);
  {
    int xr = live ? l_me : (L_SEQ - 1);
    const float* xrow = x + ((size_t)b * L_SEQ + xr) * 128;
    bf16x8 af[8];
#pragma unroll
    for (int ks = 0; ks < 8; ++ks) {
      float4 lo = *(const float4*)&xrow[ks * 16 + hi * 8];
      float4 hi4 = *(const float4*)&xrow[ks * 16 + hi * 8 + 4];
      bf16x8 v;
      v[0] = (__bf16)lo.x; v[1] = (__bf16)lo.y; v[2] = (__bf16)lo.z; v[3] = (__bf16)lo.w;
      v[4] = (__bf16)hi4.x; v[5] = (__bf16)hi4.y; v[6] = (__bf16)hi4.z; v[7] = (__bf16)hi4.w;
      af[ks] = v;
    }
#pragma unroll
    for (int r = 0; r < 3; ++r) {
      const int nt0 = g2 * 6 + 2 * r, nt1 = nt0 + 1;
      f32x16 a0 = {}, a1 = {};
#pragma unroll
      for (int ks = 0; ks < 8; ++ks) {
        bf16x8 wf0 = *(const bf16x8*)&Wb[(((nt0 * 8 + ks) * 64) + lane) * 8];
        bf16x8 wf1 = *(const bf16x8*)&Wb[(((nt1 * 8 + ks) * 64) + lane) * 8];
        a0 = __builtin_amdgcn_mfma_f32_32x32x16_bf16(wf0, af[ks], a0, 0, 0, 0);
        a1 = __builtin_amdgcn_mfma_f32_32x32x16_bf16(wf1, af[ks], a1, 0, 0, 0);
      }
      // epilogues (runtime wave-uniform qkv type)
#pragma unroll
      for (int e = 0; e < 2; ++e) {
        const int nt = e ? nt1 : nt0;
        const f32x16& A = e ? a1 : a0;
        const int h = nt / 3, qkv = nt % 3;
        if (qkv < 2) {  // q or k: RoPE in-lane on reg pairs (rg, rg+8)
          __bf16* base = (qkv == 0) ? qs : ksm;
          if (live) {
#pragma unroll
            for (int rg = 0; rg < 8; ++rg) {
              const int c_lo = (rg & 3) + 8 * (rg >> 2);
              int d = c_lo + 4 * hi;  // 0..15
              union { bf16x2 v; unsigned u; } cs;
              cs.u = tabL[l_me * 65 + 4 * d + h];
              float c = (float)cs.v[0], s = (float)cs.v[1];
              float v1 = A[rg] + bb2[nt * 32 + d];
              float v2 = A[rg + 8] + bb2[nt * 32 + d + 16];
              if (qkv == 0) { v1 *= SCALE; v2 *= SCALE; }
              union { bf16x2 v; unsigned u; } pk;
              pk.v[0] = (__bf16)(v1 * c + v2 * s);
              pk.v[1] = (__bf16)(v2 * c - v1 * s);
              *(unsigned*)&base[(h * 128 + l_me) * 40 + 2 * d] = pk.u;
            }
          }
        } else {  // v: write vT[h][d][l] XOR-swizzled
          if (live) {
#pragma unroll
            for (int rg = 0; rg < 16; ++rg) {
              const int d = (rg & 3) + 8 * (rg >> 2) + 4 * hi;  // 0..31
              float val = A[rg] + bb2[nt * 32 + d];
              vT[(h * 32 + d) * 128 + (l_me ^ ((d & 7) << 3))] = (__bf16)val;
            }
          }
        }
      }
    }
  }
  __syncthreads();

  // ======== attention: wave -> head (wv>>1); tasks qt = {wv&1, 3-(wv&1)} ====
  {
    const int h = wv >> 1;
    const int qtA = wv & 1, qtB = 3 - (wv & 1);
    // ---- preload BOTH tasks' q fragments; qs becomes yL after the barrier
    bf16x8 qf0A = *(const bf16x8*)&qs[(h * 128 + qtA * 32 + ln31) * 40 + hi * 8];
    bf16x8 qf1A = *(const bf16x8*)&qs[(h * 128 + qtA * 32 + ln31) * 40 + 16 + hi * 8];
    bf16x8 qf0B = *(const bf16x8*)&qs[(h * 128 + qtB * 32 + ln31) * 40 + hi * 8];
    bf16x8 qf1B = *(const bf16x8*)&qs[(h * 128 + qtB * 32 + ln31) * 40 + 16 + hi * 8];
    __syncthreads();  // all qs reads complete; alias qs storage as yL[128][136]
    __bf16* yL = qs;
#pragma unroll
    for (int ts = 0; ts < 2; ++ts) {
      const int qt = ts ? qtB : qtA;
      bf16x8 qf0 = ts ? qf0B : qf0A;  // static select (ts unrolled)
      bf16x8 qf1 = ts ? qf1B : qf1A;
      f32x16 s[4];
#pragma unroll
      for (int kt = 0; kt < 4; ++kt) {
        if (kt <= qt) {
          bf16x8 kf0 = *(const bf16x8*)&ksm[(h * 128 + kt * 32 + ln31) * 40 + hi * 8];
          bf16x8 kf1 = *(const bf16x8*)&ksm[(h * 128 + kt * 32 + ln31) * 40 + 16 + hi * 8];
          f32x16 z = {};
          z = __builtin_amdgcn_mfma_f32_32x32x16_bf16(kf0, qf0, z, 0, 0, 0);
          s[kt] = __builtin_amdgcn_mfma_f32_32x32x16_bf16(kf1, qf1, z, 0, 0, 0);
          if (kt == qt) {  // diagonal mask; s[] index compile-time (rule #20)
#pragma unroll
            for (int rg = 0; rg < 16; ++rg) {
              const int c_lo = (rg & 3) + 8 * (rg >> 2);
              int crow = c_lo + 4 * hi;
              s[kt][rg] = (crow <= ln31) ? s[kt][rg] : NEGINF;
            }
          }
        }
      }
      // softmax: in-lane + 1 shfl_xor(32) each for max and sum
      float mx = NEGINF;
#pragma unroll
      for (int kt = 0; kt < 4; ++kt)
        if (kt <= qt)
#pragma unroll
          for (int rg = 0; rg < 16; ++rg) mx = fmaxf(mx, s[kt][rg]);
      mx = fmaxf(mx, __shfl_xor(mx, 32));
      float sum = 0.0f;
#pragma unroll
      for (int kt = 0; kt < 4; ++kt)
        if (kt <= qt)
#pragma unroll
          for (int rg = 0; rg < 16; ++rg) {
            s[kt][rg] = __expf(s[kt][rg] - mx);
            sum += s[kt][rg];
          }
      sum += __shfl_xor(sum, 32);
      float inv = 1.0f / sum;
      unsigned pk[4][8];
#pragma unroll
      for (int kt = 0; kt < 4; ++kt) {
        if (kt <= qt) {
#pragma unroll
          for (int p = 0; p < 8; ++p) {
            union { bf16x2 v; unsigned u; } w;
            w.v[0] = (__bf16)(s[kt][2 * p] * inv);
            w.v[1] = (__bf16)(s[kt][2 * p + 1] * inv);
            pk[kt][p] = w.u;
          }
        }
      }
      f32x16 o = {};
#pragma unroll
      for (int kt = 0; kt < 4; ++kt) {
        if (kt <= qt) {
#pragma unroll
          for (int m = 0; m < 2; ++m) {
            unsigned f0 = (unsigned)__shfl_xor((int)pk[kt][4 * m + 0], 32);
            unsigned f1 = (unsigned)__shfl_xor((int)pk[kt][4 * m + 1], 32);
            unsigned f2 = (unsigned)__shfl_xor((int)pk[kt][4 * m + 2], 32);
            unsigned f3 = (unsigned)__shfl_xor((int)pk[kt][4 * m + 3], 32);
            union { unsigned w[4]; bf16x8 v; } Aw;
            Aw.w[0] = hi ? f2 : pk[kt][4 * m + 0];
            Aw.w[1] = hi ? f3 : pk[kt][4 * m + 1];
            Aw.w[2] = hi ? pk[kt][4 * m + 2] : f0;
            Aw.w[3] = hi ? pk[kt][4 * m + 3] : f1;
            bf16x8 vf = *(const bf16x8*)&vT[(h * 32 + ln31) * 128 +
                ((kt * 32 + m * 16 + hi * 8) ^ ((ln31 & 7) << 3))];
            o = __builtin_amdgcn_mfma_f32_32x32x16_bf16(Aw.v, vf, o, 0, 0, 0);
          }
        }
      }
      // y -> yL (bf16, on-CU): row = query l, col = h*32 + d
#pragma unroll
      for (int rg = 0; rg < 16; ++rg) {
        const int c_lo = (rg & 3) + 8 * (rg >> 2);
        int l = qt * 32 + c_lo + 4 * hi;
        if (l < L_SEQ)
          yL[l * 136 + h * 32 + ln31] = (__bf16)o[rg];
      }
    }
  }

  // ======== FC2 + bias + SiLU: y from LDS (yL), no global round-trip ========
  __syncthreads();
  {
    const int ln15 = lane & 15, kg = lane >> 4;
    int yr = wv * 16 + ln15;
    if (yr > L_SEQ - 1) yr = L_SEQ - 1;
    bf16x8 af2[4];
#pragma unroll
    for (int kb = 0; kb < 4; ++kb)
      af2[kb] = *(const bf16x8*)&qs[yr * 136 + kb * 32 + kg * 8];  // yL alias
    float bc[8];
#pragma unroll
    for (int nt = 0; nt < 8; ++nt) bc[nt] = bfc2[nt * 16 + ln15];
    f32x4 acc2[8] = {};
#pragma unroll
    for (int nt = 0; nt < 8; ++nt)
#pragma unroll
      for (int kb = 0; kb < 4; ++kb)
        acc2[nt] = __builtin_amdgcn_mfma_f32_16x16x32_bf16(
            af2[kb], *(const bf16x8*)&Wf2b[(((nt * 4 + kb) * 64) + lane) * 8],
            acc2[nt], 0, 0, 0);
#pragma unroll
    for (int nt = 0; nt < 8; ++nt)
#pragma unroll
      for (int r = 0; r < 4; ++r) {
        int row = wv * 16 + kg * 4 + r, c = nt * 16 + ln15;
        if (row < L_SEQ) {
          float vv = acc2[nt][r] + bc[nt];
          out[((size_t)b * L_SEQ + row) * 128 + c] = vv / (1.0f + __expf(-vv));
        }
      }
  }
}

extern "C" void kernel_launch(void* const* d_in, const int* in_sizes, int n_in,
                              void* d_out, int out_size, void* d_ws,
                              size_t ws_size, hipStream_t stream) {
  const float* x = (const float*)d_in[0];
  const float* Wqkv = (const float*)d_in[1];
  const float* bqkv = (const float*)d_in[2];
  const float* Wfc2 = (const float*)d_in[3];
  const float* bfc2 = (const float*)d_in[4];
  float* out = (float*)d_out;

  char* ws = (char*)d_ws;
  unsigned* tabu = (unsigned*)ws;                        // 30,464 B (pad 30,720)
  __bf16* Wb = (__bf16*)(ws + 30720);                    // 98,304 B
  float* bb2 = (float*)(ws + 30720 + 98304);             //  1,536 B
  __bf16* Wf2b = (__bf16*)(ws + 30720 + 98304 + 1536);   // 32,768 B (end 163,328)

  const int B = in_sizes[0] / (L_SEQ * D_MODEL);  // 2048
  prep_kernel<<<192, 256, 0, stream>>>(Wqkv, bqkv, Wfc2, tabu, Wb, bb2, Wf2b);
  fused_all<<<B, 512, 0, stream>>>(x, Wb, bb2, tabu, Wf2b, bfc2, out);
}

// Round 20
// 198.442 us; speedup vs baseline: 1.1317x; 1.0273x over previous
//
#include <hip/hip_runtime.h>
#include <hip/hip_bf16.h>
#include <math.h>

// Fused QKV(+bias) -> RoPE -> 4-head causal attention -> FC2(+bias) -> SiLU
// B=2048, L=119, D=128, H=4, HD=32. fp32 in/out, bf16 MFMA internally.
// Head split: model channel c = d*4 + h. Head merge: out channel c' = h*32 + d.
//
// Round 19: R18 base (best verified, 203.9us) + two chain cuts.
//  - Wf2b staged to LDS in the dead tabL storage (ubuf alias, 32KB): staging
//    issued right after the post-QKV barrier, latency hides under attention;
//    FC2 W-operands become ds_read_b128 (L2 traffic 256KB -> 32KB per block,
//    and the FC2 lead-in burst of 32 per-wave L2 loads disappears).
//  - log2e folded into q's scale -> softmax uses native exp2f (one fewer
//    v_mul per exp; algebraically exact: max/sum order-preserving).
// Convoy model (R17 A/B-proven): phase time = chain latency; cutting
// phase-boundary chains pays ~1:1 (R18: y-on-CU, -14us).
// Layouts (m74/m101): 32x32 C/D col=lane&31, row=(reg&3)+8*(reg>>2)+4*(lane>>5).
// A: row=lane&31, k=(lane>>5)*8+j. B: col=lane&31, same k.
// LDS: qs(=yL)/ksm 2x40,960 + vT 32,768 + ubuf(tabL->Wf2bL) 32,768 = 147,456 B.

#define L_SEQ 119
#define D_MODEL 128
// 1/sqrt(32) * log2(e): q pre-scaled so softmax exp() becomes native exp2()
#define SCALE2 (0.17677669529663687f * 1.4426950408889634f)
#define NEGINF -1e30f

typedef __bf16 bf16x8 __attribute__((ext_vector_type(8)));
typedef __bf16 bf16x2 __attribute__((ext_vector_type(2)));
typedef float f32x4 __attribute__((ext_vector_type(4)));
typedef float f32x16 __attribute__((ext_vector_type(16)));

// ---- single prep kernel: RoPE table + Wb A-frags + bb2 + Wfc2 B-frags ----
__global__ void prep_kernel(const float* __restrict__ Wqkv,
                            const float* __restrict__ bqkv,
                            const float* __restrict__ Wfc2,
                            unsigned* __restrict__ tabu,
                            __bf16* __restrict__ Wb, float* __restrict__ bb2,
                            __bf16* __restrict__ Wf2b) {
  int i = blockIdx.x * 256 + threadIdx.x;  // 0..49151
  {  // Wb (all threads)
    int j = i & 7, lane = (i >> 3) & 63, ks = (i >> 9) & 7, nt = i >> 12;
    int d = lane & 31;
    int h = nt / 3, qkv = nt % 3;
    int k = ks * 16 + (lane >> 5) * 8 + j;
    Wb[i] = (__bf16)Wqkv[(qkv * 128 + d * 4 + h) * 128 + k];
  }
  if (i < 384) {  // bb2
    int nt2 = i >> 5, dd = i & 31;
    bb2[i] = bqkv[(nt2 % 3) * 128 + dd * 4 + (nt2 / 3)];
  }
  if (i < 16384) {  // Wf2b
    int j = i & 7, lane = (i >> 3) & 63, kb = (i >> 9) & 3, nt = i >> 11;
    int n = nt * 16 + (lane & 15);
    int k = kb * 32 + (lane >> 4) * 8 + j;
    Wf2b[i] = (__bf16)Wfc2[n * 128 + k];
  }
  if (i < L_SEQ * 64) {  // RoPE table (bf16-rounded, as reference)
    int l = i >> 6, j = i & 63;
    float inv = 1.0f / powf(10000.0f, (float)(2 * j) / 128.0f);
    float f = (float)l * inv;
    union { bf16x2 v; unsigned u; } cs;
    cs.v[0] = (__bf16)cosf(f);
    cs.v[1] = (__bf16)sinf(f);
    tabu[i] = cs.u;
  }
}

__global__ __launch_bounds__(512) void fused_all(
    const float* __restrict__ x, const __bf16* __restrict__ Wb,
    const float* __restrict__ bb2, const unsigned* __restrict__ tabu,
    const __bf16* __restrict__ Wf2b, const float* __restrict__ bfc2,
    float* __restrict__ out) {
  __shared__ __align__(16) __bf16 qs[4 * 128 * 40];   // 40,960 B (yL alias later)
  __shared__ __align__(16) __bf16 ksm[4 * 128 * 40];  // 40,960 B
  __shared__ __align__(16) __bf16 vT[4 * 32 * 128];   // 32,768 B (XOR-swizzled)
  __shared__ __align__(16) unsigned char ubuf[32768]; // tabL (30,940B) -> Wf2bL

  unsigned* tabL = (unsigned*)ubuf;

  const int t = threadIdx.x, b = blockIdx.x;
  const int lane = t & 63, wv = t >> 6;
  const int ln31 = lane & 31, hi = lane >> 5;

  // ---- stage RoPE table (stride 65 words -> conflict-free lane-l reads)
  for (int i = t; i < L_SEQ * 64; i += 512)
    tabL[(i >> 6) * 65 + (i & 63)] = tabu[i];
  // ---- zero vT tail cols 119..127
  for (int i = t; i < 4 * 32 * 9; i += 512) {
    int hd = i / 9, cc = L_SEQ + i % 9, d = hd & 31;
    vT[hd * 128 + (cc ^ ((d & 7) << 3))] = (__bf16)0.0f;
  }
  __syncthreads();

  // ======== QKV: wave -> Mtile (wv&3), Ntile-group (wv>>2)*6 .. +5 ========
  const int mt = wv & 3, g2 = wv >> 2;
  const int l_me = mt * 32 + ln31;  // this lane's sequence row (col of C)
  const bool live = (l_me < L_SEQ);
  {
    int xr = live ? l_me : (L_SEQ - 1);
    const float* xrow = x + ((size_t)b * L_SEQ + xr) * 128;
    bf16x8 af[8];
#pragma unroll
    for (int ks = 0; ks < 8; ++ks) {
      float4 lo = *(const float4*)&xrow[ks * 16 + hi * 8];
      float4 hi4 = *(const float4*)&xrow[ks * 16 + hi * 8 + 4];
      bf16x8 v;
      v[0] = (__bf16)lo.x; v[1] = (__bf16)lo.y; v[2] = (__bf16)lo.z; v[3] = (__bf16)lo.w;
      v[4] = (__bf16)hi4.x; v[5] = (__bf16)hi4.y; v[6] = (__bf16)hi4.z; v[7] = (__bf16)hi4.w;
      af[ks] = v;
    }
#pragma unroll
    for (int r = 0; r < 3; ++r) {
      const int nt0 = g2 * 6 + 2 * r, nt1 = nt0 + 1;
      f32x16 a0 = {}, a1 = {};
#pragma unroll
      for (int ks = 0; ks < 8; ++ks) {
        bf16x8 wf0 = *(const bf16x8*)&Wb[(((nt0 * 8 + ks) * 64) + lane) * 8];
        bf16x8 wf1 = *(const bf16x8*)&Wb[(((nt1 * 8 + ks) * 64) + lane) * 8];
        a0 = __builtin_amdgcn_mfma_f32_32x32x16_bf16(wf0, af[ks], a0, 0, 0, 0);
        a1 = __builtin_amdgcn_mfma_f32_32x32x16_bf16(wf1, af[ks], a1, 0, 0, 0);
      }
      // epilogues (runtime wave-uniform qkv type)
#pragma unroll
      for (int e = 0; e < 2; ++e) {
        const int nt = e ? nt1 : nt0;
        const f32x16& A = e ? a1 : a0;
        const int h = nt / 3, qkv = nt % 3;
        if (qkv < 2) {  // q or k: RoPE in-lane on reg pairs (rg, rg+8)
          __bf16* base = (qkv == 0) ? qs : ksm;
          if (live) {
#pragma unroll
            for (int rg = 0; rg < 8; ++rg) {
              const int c_lo = (rg & 3) + 8 * (rg >> 2);
              int d = c_lo + 4 * hi;  // 0..15
              union { bf16x2 v; unsigned u; } cs;
              cs.u = tabL[l_me * 65 + 4 * d + h];
              float c = (float)cs.v[0], s = (float)cs.v[1];
              float v1 = A[rg] + bb2[nt * 32 + d];
              float v2 = A[rg + 8] + bb2[nt * 32 + d + 16];
              if (qkv == 0) { v1 *= SCALE2; v2 *= SCALE2; }  // incl. log2e
              union { bf16x2 v; unsigned u; } pk;
              pk.v[0] = (__bf16)(v1 * c + v2 * s);
              pk.v[1] = (__bf16)(v2 * c - v1 * s);
              *(unsigned*)&base[(h * 128 + l_me) * 40 + 2 * d] = pk.u;
            }
          }
        } else {  // v: write vT[h][d][l] XOR-swizzled
          if (live) {
#pragma unroll
            for (int rg = 0; rg < 16; ++rg) {
              const int d = (rg & 3) + 8 * (rg >> 2) + 4 * hi;  // 0..31
              float val = A[rg] + bb2[nt * 32 + d];
              vT[(h * 32 + d) * 128 + (l_me ^ ((d & 7) << 3))] = (__bf16)val;
            }
          }
        }
      }
    }
  }
  __syncthreads();  // QKV epilogue complete; tabL dead from here on

  // ---- stage Wf2b -> ubuf (overwrites dead tabL); latency hides under the
  // whole attention phase; consumed after the pre-FC2 barrier.
  {
    const uint4* wsrc = (const uint4*)Wf2b;
    uint4* wd = (uint4*)ubuf;
    wd[t] = wsrc[t];
    wd[512 + t] = wsrc[512 + t];
    wd[1024 + t] = wsrc[1024 + t];
    wd[1536 + t] = wsrc[1536 + t];
  }

  // ======== attention: wave -> head (wv>>1); tasks qt = {wv&1, 3-(wv&1)} ====
  {
    const int h = wv >> 1;
    const int qtA = wv & 1, qtB = 3 - (wv & 1);
    // ---- preload BOTH tasks' q fragments; qs becomes yL after the barrier
    bf16x8 qf0A = *(const bf16x8*)&qs[(h * 128 + qtA * 32 + ln31) * 40 + hi * 8];
    bf16x8 qf1A = *(const bf16x8*)&qs[(h * 128 + qtA * 32 + ln31) * 40 + 16 + hi * 8];
    bf16x8 qf0B = *(const bf16x8*)&qs[(h * 128 + qtB * 32 + ln31) * 40 + hi * 8];
    bf16x8 qf1B = *(const bf16x8*)&qs[(h * 128 + qtB * 32 + ln31) * 40 + 16 + hi * 8];
    __syncthreads();  // all qs reads complete; alias qs storage as yL[128][136]
    __bf16* yL = qs;
#pragma unroll
    for (int ts = 0; ts < 2; ++ts) {
      const int qt = ts ? qtB : qtA;
      bf16x8 qf0 = ts ? qf0B : qf0A;  // static select (ts unrolled)
      bf16x8 qf1 = ts ? qf1B : qf1A;
      f32x16 s[4];
#pragma unroll
      for (int kt = 0; kt < 4; ++kt) {
        if (kt <= qt) {
          bf16x8 kf0 = *(const bf16x8*)&ksm[(h * 128 + kt * 32 + ln31) * 40 + hi * 8];
          bf16x8 kf1 = *(const bf16x8*)&ksm[(h * 128 + kt * 32 + ln31) * 40 + 16 + hi * 8];
          f32x16 z = {};
          z = __builtin_amdgcn_mfma_f32_32x32x16_bf16(kf0, qf0, z, 0, 0, 0);
          s[kt] = __builtin_amdgcn_mfma_f32_32x32x16_bf16(kf1, qf1, z, 0, 0, 0);
          if (kt == qt) {  // diagonal mask; s[] index compile-time (rule #20)
#pragma unroll
            for (int rg = 0; rg < 16; ++rg) {
              const int c_lo = (rg & 3) + 8 * (rg >> 2);
              int crow = c_lo + 4 * hi;
              s[kt][rg] = (crow <= ln31) ? s[kt][rg] : NEGINF;
            }
          }
        }
      }
      // softmax in log2 domain: in-lane + 1 shfl_xor(32) each for max and sum
      float mx = NEGINF;
#pragma unroll
      for (int kt = 0; kt < 4; ++kt)
        if (kt <= qt)
#pragma unroll
          for (int rg = 0; rg < 16; ++rg) mx = fmaxf(mx, s[kt][rg]);
      mx = fmaxf(mx, __shfl_xor(mx, 32));
      float sum = 0.0f;
#pragma unroll
      for (int kt = 0; kt < 4; ++kt)
        if (kt <= qt)
#pragma unroll
          for (int rg = 0; rg < 16; ++rg) {
            s[kt][rg] = exp2f(s[kt][rg] - mx);  // native v_exp_f32
            sum += s[kt][rg];
          }
      sum += __shfl_xor(sum, 32);
      float inv = 1.0f / sum;
      unsigned pk[4][8];
#pragma unroll
      for (int kt = 0; kt < 4; ++kt) {
        if (kt <= qt) {
#pragma unroll
          for (int p = 0; p < 8; ++p) {
            union { bf16x2 v; unsigned u; } w;
            w.v[0] = (__bf16)(s[kt][2 * p] * inv);
            w.v[1] = (__bf16)(s[kt][2 * p + 1] * inv);
            pk[kt][p] = w.u;
          }
        }
      }
      f32x16 o = {};
#pragma unroll
      for (int kt = 0; kt < 4; ++kt) {
        if (kt <= qt) {
#pragma unroll
          for (int m = 0; m < 2; ++m) {
            unsigned f0 = (unsigned)__shfl_xor((int)pk[kt][4 * m + 0], 32);
            unsigned f1 = (unsigned)__shfl_xor((int)pk[kt][4 * m + 1], 32);
            unsigned f2 = (unsigned)__shfl_xor((int)pk[kt][4 * m + 2], 32);
            unsigned f3 = (unsigned)__shfl_xor((int)pk[kt][4 * m + 3], 32);
            union { unsigned w[4]; bf16x8 v; } Aw;
            Aw.w[0] = hi ? f2 : pk[kt][4 * m + 0];
            Aw.w[1] = hi ? f3 : pk[kt][4 * m + 1];
            Aw.w[2] = hi ? pk[kt][4 * m + 2] : f0;
            Aw.w[3] = hi ? pk[kt][4 * m + 3] : f1;
            bf16x8 vf = *(const bf16x8*)&vT[(h * 32 + ln31) * 128 +
                ((kt * 32 + m * 16 + hi * 8) ^ ((ln31 & 7) << 3))];
            o = __builtin_amdgcn_mfma_f32_32x32x16_bf16(Aw.v, vf, o, 0, 0, 0);
          }
        }
      }
      // y -> yL (bf16, on-CU): row = query l, col = h*32 + d
#pragma unroll
      for (int rg = 0; rg < 16; ++rg) {
        const int c_lo = (rg & 3) + 8 * (rg >> 2);
        int l = qt * 32 + c_lo + 4 * hi;
        if (l < L_SEQ)
          yL[l * 136 + h * 32 + ln31] = (__bf16)o[rg];
      }
    }
  }

  // ======== FC2 + bias + SiLU: y from LDS (yL), W from LDS (ubuf) ========
  __syncthreads();
  {
    const __bf16* Wf2bL = (const __bf16*)ubuf;
    const int ln15 = lane & 15, kg = lane >> 4;
    int yr = wv * 16 + ln15;
    if (yr > L_SEQ - 1) yr = L_SEQ - 1;
    bf16x8 af2[4];
#pragma unroll
    for (int kb = 0; kb < 4; ++kb)
      af2[kb] = *(const bf16x8*)&qs[yr * 136 + kb * 32 + kg * 8];  // yL alias
    float bc[8];
#pragma unroll
    for (int nt = 0; nt < 8; ++nt) bc[nt] = bfc2[nt * 16 + ln15];
    f32x4 acc2[8] = {};
#pragma unroll
    for (int nt = 0; nt < 8; ++nt)
#pragma unroll
      for (int kb = 0; kb < 4; ++kb)
        acc2[nt] = __builtin_amdgcn_mfma_f32_16x16x32_bf16(
            af2[kb], *(const bf16x8*)&Wf2bL[(((nt * 4 + kb) * 64) + lane) * 8],
            acc2[nt], 0, 0, 0);
#pragma unroll
    for (int nt = 0; nt < 8; ++nt)
#pragma unroll
      for (int r = 0; r < 4; ++r) {
        int row = wv * 16 + kg * 4 + r, c = nt * 16 + ln15;
        if (row < L_SEQ) {
          float vv = acc2[nt][r] + bc[nt];
          out[((size_t)b * L_SEQ + row) * 128 + c] = vv / (1.0f + __expf(-vv));
        }
      }
  }
}

extern "C" void kernel_launch(void* const* d_in, const int* in_sizes, int n_in,
                              void* d_out, int out_size, void* d_ws,
                              size_t ws_size, hipStream_t stream) {
  const float* x = (const float*)d_in[0];
  const float* Wqkv = (const float*)d_in[1];
  const float* bqkv = (const float*)d_in[2];
  const float* Wfc2 = (const float*)d_in[3];
  const float* bfc2 = (const float*)d_in[4];
  float* out = (float*)d_out;

  char* ws = (char*)d_ws;
  unsigned* tabu = (unsigned*)ws;                        // 30,464 B (pad 30,720)
  __bf16* Wb = (__bf16*)(ws + 30720);                    // 98,304 B
  float* bb2 = (float*)(ws + 30720 + 98304);             //  1,536 B
  __bf16* Wf2b = (__bf16*)(ws + 30720 + 98304 + 1536);   // 32,768 B (end 163,328)

  const int B = in_sizes[0] / (L_SEQ * D_MODEL);  // 2048
  prep_kernel<<<192, 256, 0, stream>>>(Wqkv, bqkv, Wfc2, tabu, Wb, bb2, Wf2b);
  fused_all<<<B, 512, 0, stream>>>(x, Wb, bb2, tabu, Wf2b, bfc2, out);
}

// Round 21
// 193.466 us; speedup vs baseline: 1.1608x; 1.0257x over previous
//
#include <hip/hip_runtime.h>
#include <hip/hip_bf16.h>
#include <math.h>

// Fused QKV(+bias) -> RoPE -> 4-head causal attention -> FC2(+bias) -> SiLU
// B=2048, L=119, D=128, H=4, HD=32. fp32 in/out, bf16 MFMA internally.
// Head split: model channel c = d*4 + h. Head merge: out channel c' = h*32 + d.
//
// Round 20: R19 base (best verified, 198.4us) + QKV-epilogue gather cuts.
//  - RoPE table repacked per-head contiguous-d (tab2[h][l][d], prep-side),
//    staged at LDS row stride 18 dwords (even -> b64-aligned): rg-pair reads
//    one ds_read_b64 (8 b32 -> 4 b64 per q/k instance).
//  - bb2 biases staged to LDS (1.5KB), read as float2 (adjacent d after the
//    repack): 32 per-lane GLOBAL gather loads per instance -> 8-12 LDS b64.
//  - q/k pk stores packed to uint2 (adjacent d -> contiguous dwords).
// Convoy model (R17 A/B): phase time = chain latency; cuts pay ~1:1
// (R18 y-on-CU -14us, R19 Wf2b-LDS+exp2 -5.5us).
// Layouts (m74/m101): 32x32 C/D col=lane&31, row=(reg&3)+8*(reg>>2)+4*(lane>>5).
// A: row=lane&31, k=(lane>>5)*8+j. B: col=lane&31, same k.
// LDS: qs(=yL)/ksm 2x40,960 + vT 32,768 + ubuf(tabL2->Wf2bL) 34,304 +
// bb2L 1,536 = 150,528 B.

#define L_SEQ 119
#define D_MODEL 128
// 1/sqrt(32) * log2(e): q pre-scaled so softmax exp() becomes native exp2()
#define SCALE2 (0.17677669529663687f * 1.4426950408889634f)
#define NEGINF -1e30f

typedef __bf16 bf16x8 __attribute__((ext_vector_type(8)));
typedef __bf16 bf16x2 __attribute__((ext_vector_type(2)));
typedef float f32x4 __attribute__((ext_vector_type(4)));
typedef float f32x16 __attribute__((ext_vector_type(16)));

// ---- single prep kernel: RoPE table (per-head packed) + Wb + bb2 + Wf2b ----
__global__ void prep_kernel(const float* __restrict__ Wqkv,
                            const float* __restrict__ bqkv,
                            const float* __restrict__ Wfc2,
                            unsigned* __restrict__ tab2,
                            __bf16* __restrict__ Wb, float* __restrict__ bb2,
                            __bf16* __restrict__ Wf2b) {
  int i = blockIdx.x * 256 + threadIdx.x;  // 0..49151
  {  // Wb (all threads): flat = ((nt*8 + ks)*64 + lane)*8 + j
    int j = i & 7, lane = (i >> 3) & 63, ks = (i >> 9) & 7, nt = i >> 12;
    int d = lane & 31;
    int h = nt / 3, qkv = nt % 3;
    int k = ks * 16 + (lane >> 5) * 8 + j;
    Wb[i] = (__bf16)Wqkv[(qkv * 128 + d * 4 + h) * 128 + k];
  }
  if (i < 384) {  // bb2
    int nt2 = i >> 5, dd = i & 31;
    bb2[i] = bqkv[(nt2 % 3) * 128 + dd * 4 + (nt2 / 3)];
  }
  if (i < 16384) {  // Wf2b: flat = ((nt*4 + kb)*64 + lane)*8 + j
    int j = i & 7, lane = (i >> 3) & 63, kb = (i >> 9) & 3, nt = i >> 11;
    int n = nt * 16 + (lane & 15);
    int k = kb * 32 + (lane >> 4) * 8 + j;
    Wf2b[i] = (__bf16)Wfc2[n * 128 + k];
  }
  if (i < 4 * L_SEQ * 16) {  // RoPE table, per-head packed: tab2[h][l][d]
    int h = i / (L_SEQ * 16), rem = i % (L_SEQ * 16);
    int l = rem >> 4, d = rem & 15;
    int j = 4 * d + h;  // freq index for head h, head-dim pair (d, d+16)
    float inv = 1.0f / powf(10000.0f, (float)(2 * j) / 128.0f);
    float f = (float)l * inv;
    union { bf16x2 v; unsigned u; } cs;
    cs.v[0] = (__bf16)cosf(f);
    cs.v[1] = (__bf16)sinf(f);
    tab2[i] = cs.u;
  }
}

__global__ __launch_bounds__(512) void fused_all(
    const float* __restrict__ x, const __bf16* __restrict__ Wb,
    const float* __restrict__ bb2, const unsigned* __restrict__ tab2,
    const __bf16* __restrict__ Wf2b, const float* __restrict__ bfc2,
    float* __restrict__ out) {
  __shared__ __align__(16) __bf16 qs[4 * 128 * 40];   // 40,960 B (yL alias later)
  __shared__ __align__(16) __bf16 ksm[4 * 128 * 40];  // 40,960 B
  __shared__ __align__(16) __bf16 vT[4 * 32 * 128];   // 32,768 B (XOR-swizzled)
  __shared__ __align__(16) unsigned char ubuf[34304]; // tabL2 (34,272B) -> Wf2bL
  __shared__ float bb2L[384];                         // 1,536 B

  unsigned* tabL2 = (unsigned*)ubuf;  // [4][119][18] dwords, 16 used/row

  const int t = threadIdx.x, b = blockIdx.x;
  const int lane = t & 63, wv = t >> 6;
  const int ln31 = lane & 31, hi = lane >> 5;

  // ---- stage RoPE table (row stride 18 dwords: even -> b64-aligned reads)
  for (int i = t; i < 4 * L_SEQ * 16; i += 512) {
    int h = i / (L_SEQ * 16), rem = i % (L_SEQ * 16);
    int l = rem >> 4, d = rem & 15;
    tabL2[(h * L_SEQ + l) * 18 + d] = tab2[i];
  }
  if (t < 384) bb2L[t] = bb2[t];
  // ---- zero vT tail cols 119..127
  for (int i = t; i < 4 * 32 * 9; i += 512) {
    int hd = i / 9, cc = L_SEQ + i % 9, d = hd & 31;
    vT[hd * 128 + (cc ^ ((d & 7) << 3))] = (__bf16)0.0f;
  }
  __syncthreads();

  // ======== QKV: wave -> Mtile (wv&3), Ntile-group (wv>>2)*6 .. +5 ========
  const int mt = wv & 3, g2 = wv >> 2;
  const int l_me = mt * 32 + ln31;  // this lane's sequence row (col of C)
  const bool live = (l_me < L_SEQ);
  {
    int xr = live ? l_me : (L_SEQ - 1);
    const float* xrow = x + ((size_t)b * L_SEQ + xr) * 128;
    bf16x8 af[8];
#pragma unroll
    for (int ks = 0; ks < 8; ++ks) {
      float4 lo = *(const float4*)&xrow[ks * 16 + hi * 8];
      float4 hi4 = *(const float4*)&xrow[ks * 16 + hi * 8 + 4];
      bf16x8 v;
      v[0] = (__bf16)lo.x; v[1] = (__bf16)lo.y; v[2] = (__bf16)lo.z; v[3] = (__bf16)lo.w;
      v[4] = (__bf16)hi4.x; v[5] = (__bf16)hi4.y; v[6] = (__bf16)hi4.z; v[7] = (__bf16)hi4.w;
      af[ks] = v;
    }
#pragma unroll
    for (int r = 0; r < 3; ++r) {
      const int nt0 = g2 * 6 + 2 * r, nt1 = nt0 + 1;
      f32x16 a0 = {}, a1 = {};
#pragma unroll
      for (int ks = 0; ks < 8; ++ks) {
        bf16x8 wf0 = *(const bf16x8*)&Wb[(((nt0 * 8 + ks) * 64) + lane) * 8];
        bf16x8 wf1 = *(const bf16x8*)&Wb[(((nt1 * 8 + ks) * 64) + lane) * 8];
        a0 = __builtin_amdgcn_mfma_f32_32x32x16_bf16(wf0, af[ks], a0, 0, 0, 0);
        a1 = __builtin_amdgcn_mfma_f32_32x32x16_bf16(wf1, af[ks], a1, 0, 0, 0);
      }
      // epilogues (runtime wave-uniform qkv type)
#pragma unroll
      for (int e = 0; e < 2; ++e) {
        const int nt = e ? nt1 : nt0;
        const f32x16& A = e ? a1 : a0;
        const int h = nt / 3, qkv = nt % 3;
        if (qkv < 2) {  // q or k: RoPE in-lane on reg pairs (rg, rg+8)
          __bf16* base = (qkv == 0) ? qs : ksm;
          if (live) {
            const int rowb = (h * L_SEQ + l_me) * 18;
#pragma unroll
            for (int rp = 0; rp < 4; ++rp) {
              const int rg = rp * 2;
              const int c_lo = (rg & 3) + 8 * (rg >> 2);  // 0,2,8,10
              const int d0 = c_lo + 4 * hi;               // even
              uint2 cs2 = *(const uint2*)&tabL2[rowb + d0];
              float2 bA = *(const float2*)&bb2L[nt * 32 + d0];
              float2 bB = *(const float2*)&bb2L[nt * 32 + d0 + 16];
              union { bf16x2 v; unsigned u; } c0, c1, p0, p1;
              c0.u = cs2.x; c1.u = cs2.y;
              float v1a = A[rg] + bA.x, v2a = A[rg + 8] + bB.x;
              float v1b = A[rg + 1] + bA.y, v2b = A[rg + 9] + bB.y;
              if (qkv == 0) { v1a *= SCALE2; v2a *= SCALE2; v1b *= SCALE2; v2b *= SCALE2; }
              float ca = (float)c0.v[0], sa = (float)c0.v[1];
              float cb = (float)c1.v[0], sb = (float)c1.v[1];
              p0.v[0] = (__bf16)(v1a * ca + v2a * sa);
              p0.v[1] = (__bf16)(v2a * ca - v1a * sa);
              p1.v[0] = (__bf16)(v1b * cb + v2b * sb);
              p1.v[1] = (__bf16)(v2b * cb - v1b * sb);
              uint2 pkw; pkw.x = p0.u; pkw.y = p1.u;
              *(uint2*)&base[(h * 128 + l_me) * 40 + 2 * d0] = pkw;
            }
          }
        } else {  // v: write vT[h][d][l] XOR-swizzled
          if (live) {
#pragma unroll
            for (int rp = 0; rp < 8; ++rp) {
              const int rg = rp * 2;
              const int d0 = (rg & 3) + 8 * (rg >> 2) + 4 * hi;  // even, 0..30
              float2 bv = *(const float2*)&bb2L[nt * 32 + d0];
              float val0 = A[rg] + bv.x;
              float val1 = A[rg + 1] + bv.y;
              vT[(h * 32 + d0) * 128 + (l_me ^ ((d0 & 7) << 3))] = (__bf16)val0;
              vT[(h * 32 + d0 + 1) * 128 + (l_me ^ (((d0 + 1) & 7) << 3))] = (__bf16)val1;
            }
          }
        }
      }
    }
  }
  __syncthreads();  // QKV epilogue complete; tabL2 dead from here on

  // ---- stage Wf2b -> ubuf (overwrites dead tabL2); latency hides under the
  // whole attention phase; consumed after the pre-FC2 barrier.
  {
    const uint4* wsrc = (const uint4*)Wf2b;
    uint4* wd = (uint4*)ubuf;
    wd[t] = wsrc[t];
    wd[512 + t] = wsrc[512 + t];
    wd[1024 + t] = wsrc[1024 + t];
    wd[1536 + t] = wsrc[1536 + t];
  }

  // ======== attention: wave -> head (wv>>1); tasks qt = {wv&1, 3-(wv&1)} ====
  {
    const int h = wv >> 1;
    const int qtA = wv & 1, qtB = 3 - (wv & 1);
    // ---- preload BOTH tasks' q fragments; qs becomes yL after the barrier
    bf16x8 qf0A = *(const bf16x8*)&qs[(h * 128 + qtA * 32 + ln31) * 40 + hi * 8];
    bf16x8 qf1A = *(const bf16x8*)&qs[(h * 128 + qtA * 32 + ln31) * 40 + 16 + hi * 8];
    bf16x8 qf0B = *(const bf16x8*)&qs[(h * 128 + qtB * 32 + ln31) * 40 + hi * 8];
    bf16x8 qf1B = *(const bf16x8*)&qs[(h * 128 + qtB * 32 + ln31) * 40 + 16 + hi * 8];
    __syncthreads();  // all qs reads complete; alias qs storage as yL[128][136]
    __bf16* yL = qs;
#pragma unroll
    for (int ts = 0; ts < 2; ++ts) {
      const int qt = ts ? qtB : qtA;
      bf16x8 qf0 = ts ? qf0B : qf0A;  // static select (ts unrolled)
      bf16x8 qf1 = ts ? qf1B : qf1A;
      f32x16 s[4];
#pragma unroll
      for (int kt = 0; kt < 4; ++kt) {
        if (kt <= qt) {
          bf16x8 kf0 = *(const bf16x8*)&ksm[(h * 128 + kt * 32 + ln31) * 40 + hi * 8];
          bf16x8 kf1 = *(const bf16x8*)&ksm[(h * 128 + kt * 32 + ln31) * 40 + 16 + hi * 8];
          f32x16 z = {};
          z = __builtin_amdgcn_mfma_f32_32x32x16_bf16(kf0, qf0, z, 0, 0, 0);
          s[kt] = __builtin_amdgcn_mfma_f32_32x32x16_bf16(kf1, qf1, z, 0, 0, 0);
          if (kt == qt) {  // diagonal mask; s[] index compile-time (rule #20)
#pragma unroll
            for (int rg = 0; rg < 16; ++rg) {
              const int c_lo = (rg & 3) + 8 * (rg >> 2);
              int crow = c_lo + 4 * hi;
              s[kt][rg] = (crow <= ln31) ? s[kt][rg] : NEGINF;
            }
          }
        }
      }
      // softmax in log2 domain: in-lane + 1 shfl_xor(32) each for max and sum
      float mx = NEGINF;
#pragma unroll
      for (int kt = 0; kt < 4; ++kt)
        if (kt <= qt)
#pragma unroll
          for (int rg = 0; rg < 16; ++rg) mx = fmaxf(mx, s[kt][rg]);
      mx = fmaxf(mx, __shfl_xor(mx, 32));
      float sum = 0.0f;
#pragma unroll
      for (int kt = 0; kt < 4; ++kt)
        if (kt <= qt)
#pragma unroll
          for (int rg = 0; rg < 16; ++rg) {
            s[kt][rg] = exp2f(s[kt][rg] - mx);  // native v_exp_f32
            sum += s[kt][rg];
          }
      sum += __shfl_xor(sum, 32);
      float inv = 1.0f / sum;
      unsigned pk[4][8];
#pragma unroll
      for (int kt = 0; kt < 4; ++kt) {
        if (kt <= qt) {
#pragma unroll
          for (int p = 0; p < 8; ++p) {
            union { bf16x2 v; unsigned u; } w;
            w.v[0] = (__bf16)(s[kt][2 * p] * inv);
            w.v[1] = (__bf16)(s[kt][2 * p + 1] * inv);
            pk[kt][p] = w.u;
          }
        }
      }
      f32x16 o = {};
#pragma unroll
      for (int kt = 0; kt < 4; ++kt) {
        if (kt <= qt) {
#pragma unroll
          for (int m = 0; m < 2; ++m) {
            unsigned f0 = (unsigned)__shfl_xor((int)pk[kt][4 * m + 0], 32);
            unsigned f1 = (unsigned)__shfl_xor((int)pk[kt][4 * m + 1], 32);
            unsigned f2 = (unsigned)__shfl_xor((int)pk[kt][4 * m + 2], 32);
            unsigned f3 = (unsigned)__shfl_xor((int)pk[kt][4 * m + 3], 32);
            union { unsigned w[4]; bf16x8 v; } Aw;
            Aw.w[0] = hi ? f2 : pk[kt][4 * m + 0];
            Aw.w[1] = hi ? f3 : pk[kt][4 * m + 1];
            Aw.w[2] = hi ? pk[kt][4 * m + 2] : f0;
            Aw.w[3] = hi ? pk[kt][4 * m + 3] : f1;
            bf16x8 vf = *(const bf16x8*)&vT[(h * 32 + ln31) * 128 +
                ((kt * 32 + m * 16 + hi * 8) ^ ((ln31 & 7) << 3))];
            o = __builtin_amdgcn_mfma_f32_32x32x16_bf16(Aw.v, vf, o, 0, 0, 0);
          }
        }
      }
      // y -> yL (bf16, on-CU): row = query l, col = h*32 + d
#pragma unroll
      for (int rg = 0; rg < 16; ++rg) {
        const int c_lo = (rg & 3) + 8 * (rg >> 2);
        int l = qt * 32 + c_lo + 4 * hi;
        if (l < L_SEQ)
          yL[l * 136 + h * 32 + ln31] = (__bf16)o[rg];
      }
    }
  }

  // ======== FC2 + bias + SiLU: y from LDS (yL), W from LDS (ubuf) ========
  __syncthreads();
  {
    const __bf16* Wf2bL = (const __bf16*)ubuf;
    const int ln15 = lane & 15, kg = lane >> 4;
    int yr = wv * 16 + ln15;
    if (yr > L_SEQ - 1) yr = L_SEQ - 1;
    bf16x8 af2[4];
#pragma unroll
    for (int kb = 0; kb < 4; ++kb)
      af2[kb] = *(const bf16x8*)&qs[yr * 136 + kb * 32 + kg * 8];  // yL alias
    float bc[8];
#pragma unroll
    for (int nt = 0; nt < 8; ++nt) bc[nt] = bfc2[nt * 16 + ln15];
    f32x4 acc2[8] = {};
#pragma unroll
    for (int nt = 0; nt < 8; ++nt)
#pragma unroll
      for (int kb = 0; kb < 4; ++kb)
        acc2[nt] = __builtin_amdgcn_mfma_f32_16x16x32_bf16(
            af2[kb], *(const bf16x8*)&Wf2bL[(((nt * 4 + kb) * 64) + lane) * 8],
            acc2[nt], 0, 0, 0);
#pragma unroll
    for (int nt = 0; nt < 8; ++nt)
#pragma unroll
      for (int r = 0; r < 4; ++r) {
        int row = wv * 16 + kg * 4 + r, c = nt * 16 + ln15;
        if (row < L_SEQ) {
          float vv = acc2[nt][r] + bc[nt];
          out[((size_t)b * L_SEQ + row) * 128 + c] = vv / (1.0f + __expf(-vv));
        }
      }
  }
}

extern "C" void kernel_launch(void* const* d_in, const int* in_sizes, int n_in,
                              void* d_out, int out_size, void* d_ws,
                              size_t ws_size, hipStream_t stream) {
  const float* x = (const float*)d_in[0];
  const float* Wqkv = (const float*)d_in[1];
  const float* bqkv = (const float*)d_in[2];
  const float* Wfc2 = (const float*)d_in[3];
  const float* bfc2 = (const float*)d_in[4];
  float* out = (float*)d_out;

  char* ws = (char*)d_ws;
  unsigned* tab2 = (unsigned*)ws;                        // 30,464 B (pad 30,720)
  __bf16* Wb = (__bf16*)(ws + 30720);                    // 98,304 B
  float* bb2 = (float*)(ws + 30720 + 98304);             //  1,536 B
  __bf16* Wf2b = (__bf16*)(ws + 30720 + 98304 + 1536);   // 32,768 B (end 163,328)

  const int B = in_sizes[0] / (L_SEQ * D_MODEL);  // 2048
  prep_kernel<<<192, 256, 0, stream>>>(Wqkv, bqkv, Wfc2, tab2, Wb, bb2, Wf2b);
  fused_all<<<B, 512, 0, stream>>>(x, Wb, bb2, tab2, Wf2b, bfc2, out);
}

// Round 22
// 187.896 us; speedup vs baseline: 1.1952x; 1.0296x over previous
//
#include <hip/hip_runtime.h>
#include <hip/hip_bf16.h>
#include <math.h>

// Fused QKV(+bias) -> RoPE -> 4-head causal attention -> FC2(+bias) -> SiLU
// B=2048, L=119, D=128, H=4, HD=32. fp32 in/out, bf16 MFMA internally.
// Head split: model channel c = d*4 + h. Head merge: out channel c' = h*32 + d.
//
// Round 21: R20 base (best verified, 193.5us) + final chain cut: bfc2 (the
// last remaining GLOBAL gather in the block body -- 8 per-lane loads on the
// FC2 lead-in) staged into the dead bb2L LDS region right after the post-QKV
// barrier (write hidden under attention; read after the pre-FC2 barrier --
// same proven pattern as Wf2b->ubuf).
// Convoy model (R17 A/B-proven): phase time = chain latency; chain cuts pay
// ~1:1 (R18 y-on-CU -14us, R19 Wf2b-LDS+exp2 -5.5us, R20 gather cuts -5us).
// Pre-committed: if this lands <2us, the convoy plateau is declared -- no pipe
// >39%, every throughput lever measured-null, remaining gap is distributed
// per-wave chain latency needing an inline-asm async rewrite.
// Layouts (m74/m101): 32x32 C/D col=lane&31, row=(reg&3)+8*(reg>>2)+4*(lane>>5).
// A: row=lane&31, k=(lane>>5)*8+j. B: col=lane&31, same k.
// LDS: qs(=yL)/ksm 2x40,960 + vT 32,768 + ubuf(tabL2->Wf2bL) 34,304 +
// bb2L(->bfc2L) 1,536 = 150,528 B.

#define L_SEQ 119
#define D_MODEL 128
// 1/sqrt(32) * log2(e): q pre-scaled so softmax exp() becomes native exp2()
#define SCALE2 (0.17677669529663687f * 1.4426950408889634f)
#define NEGINF -1e30f

typedef __bf16 bf16x8 __attribute__((ext_vector_type(8)));
typedef __bf16 bf16x2 __attribute__((ext_vector_type(2)));
typedef float f32x4 __attribute__((ext_vector_type(4)));
typedef float f32x16 __attribute__((ext_vector_type(16)));

// ---- single prep kernel: RoPE table (per-head packed) + Wb + bb2 + Wf2b ----
__global__ void prep_kernel(const float* __restrict__ Wqkv,
                            const float* __restrict__ bqkv,
                            const float* __restrict__ Wfc2,
                            unsigned* __restrict__ tab2,
                            __bf16* __restrict__ Wb, float* __restrict__ bb2,
                            __bf16* __restrict__ Wf2b) {
  int i = blockIdx.x * 256 + threadIdx.x;  // 0..49151
  {  // Wb (all threads): flat = ((nt*8 + ks)*64 + lane)*8 + j
    int j = i & 7, lane = (i >> 3) & 63, ks = (i >> 9) & 7, nt = i >> 12;
    int d = lane & 31;
    int h = nt / 3, qkv = nt % 3;
    int k = ks * 16 + (lane >> 5) * 8 + j;
    Wb[i] = (__bf16)Wqkv[(qkv * 128 + d * 4 + h) * 128 + k];
  }
  if (i < 384) {  // bb2
    int nt2 = i >> 5, dd = i & 31;
    bb2[i] = bqkv[(nt2 % 3) * 128 + dd * 4 + (nt2 / 3)];
  }
  if (i < 16384) {  // Wf2b: flat = ((nt*4 + kb)*64 + lane)*8 + j
    int j = i & 7, lane = (i >> 3) & 63, kb = (i >> 9) & 3, nt = i >> 11;
    int n = nt * 16 + (lane & 15);
    int k = kb * 32 + (lane >> 4) * 8 + j;
    Wf2b[i] = (__bf16)Wfc2[n * 128 + k];
  }
  if (i < 4 * L_SEQ * 16) {  // RoPE table, per-head packed: tab2[h][l][d]
    int h = i / (L_SEQ * 16), rem = i % (L_SEQ * 16);
    int l = rem >> 4, d = rem & 15;
    int j = 4 * d + h;  // freq index for head h, head-dim pair (d, d+16)
    float inv = 1.0f / powf(10000.0f, (float)(2 * j) / 128.0f);
    float f = (float)l * inv;
    union { bf16x2 v; unsigned u; } cs;
    cs.v[0] = (__bf16)cosf(f);
    cs.v[1] = (__bf16)sinf(f);
    tab2[i] = cs.u;
  }
}

__global__ __launch_bounds__(512) void fused_all(
    const float* __restrict__ x, const __bf16* __restrict__ Wb,
    const float* __restrict__ bb2, const unsigned* __restrict__ tab2,
    const __bf16* __restrict__ Wf2b, const float* __restrict__ bfc2,
    float* __restrict__ out) {
  __shared__ __align__(16) __bf16 qs[4 * 128 * 40];   // 40,960 B (yL alias later)
  __shared__ __align__(16) __bf16 ksm[4 * 128 * 40];  // 40,960 B
  __shared__ __align__(16) __bf16 vT[4 * 32 * 128];   // 32,768 B (XOR-swizzled)
  __shared__ __align__(16) unsigned char ubuf[34304]; // tabL2 (34,272B) -> Wf2bL
  __shared__ float bb2L[384];                         // 1,536 B (-> bfc2L after QKV)

  unsigned* tabL2 = (unsigned*)ubuf;  // [4][119][18] dwords, 16 used/row

  const int t = threadIdx.x, b = blockIdx.x;
  const int lane = t & 63, wv = t >> 6;
  const int ln31 = lane & 31, hi = lane >> 5;

  // ---- stage RoPE table (row stride 18 dwords: even -> b64-aligned reads)
  for (int i = t; i < 4 * L_SEQ * 16; i += 512) {
    int h = i / (L_SEQ * 16), rem = i % (L_SEQ * 16);
    int l = rem >> 4, d = rem & 15;
    tabL2[(h * L_SEQ + l) * 18 + d] = tab2[i];
  }
  if (t < 384) bb2L[t] = bb2[t];
  // ---- zero vT tail cols 119..127
  for (int i = t; i < 4 * 32 * 9; i += 512) {
    int hd = i / 9, cc = L_SEQ + i % 9, d = hd & 31;
    vT[hd * 128 + (cc ^ ((d & 7) << 3))] = (__bf16)0.0f;
  }
  __syncthreads();

  // ======== QKV: wave -> Mtile (wv&3), Ntile-group (wv>>2)*6 .. +5 ========
  const int mt = wv & 3, g2 = wv >> 2;
  const int l_me = mt * 32 + ln31;  // this lane's sequence row (col of C)
  const bool live = (l_me < L_SEQ);
  {
    int xr = live ? l_me : (L_SEQ - 1);
    const float* xrow = x + ((size_t)b * L_SEQ + xr) * 128;
    bf16x8 af[8];
#pragma unroll
    for (int ks = 0; ks < 8; ++ks) {
      float4 lo = *(const float4*)&xrow[ks * 16 + hi * 8];
      float4 hi4 = *(const float4*)&xrow[ks * 16 + hi * 8 + 4];
      bf16x8 v;
      v[0] = (__bf16)lo.x; v[1] = (__bf16)lo.y; v[2] = (__bf16)lo.z; v[3] = (__bf16)lo.w;
      v[4] = (__bf16)hi4.x; v[5] = (__bf16)hi4.y; v[6] = (__bf16)hi4.z; v[7] = (__bf16)hi4.w;
      af[ks] = v;
    }
#pragma unroll
    for (int r = 0; r < 3; ++r) {
      const int nt0 = g2 * 6 + 2 * r, nt1 = nt0 + 1;
      f32x16 a0 = {}, a1 = {};
#pragma unroll
      for (int ks = 0; ks < 8; ++ks) {
        bf16x8 wf0 = *(const bf16x8*)&Wb[(((nt0 * 8 + ks) * 64) + lane) * 8];
        bf16x8 wf1 = *(const bf16x8*)&Wb[(((nt1 * 8 + ks) * 64) + lane) * 8];
        a0 = __builtin_amdgcn_mfma_f32_32x32x16_bf16(wf0, af[ks], a0, 0, 0, 0);
        a1 = __builtin_amdgcn_mfma_f32_32x32x16_bf16(wf1, af[ks], a1, 0, 0, 0);
      }
      // epilogues (runtime wave-uniform qkv type)
#pragma unroll
      for (int e = 0; e < 2; ++e) {
        const int nt = e ? nt1 : nt0;
        const f32x16& A = e ? a1 : a0;
        const int h = nt / 3, qkv = nt % 3;
        if (qkv < 2) {  // q or k: RoPE in-lane on reg pairs (rg, rg+8)
          __bf16* base = (qkv == 0) ? qs : ksm;
          if (live) {
            const int rowb = (h * L_SEQ + l_me) * 18;
#pragma unroll
            for (int rp = 0; rp < 4; ++rp) {
              const int rg = rp * 2;
              const int c_lo = (rg & 3) + 8 * (rg >> 2);  // 0,2,8,10
              const int d0 = c_lo + 4 * hi;               // even
              uint2 cs2 = *(const uint2*)&tabL2[rowb + d0];
              float2 bA = *(const float2*)&bb2L[nt * 32 + d0];
              float2 bB = *(const float2*)&bb2L[nt * 32 + d0 + 16];
              union { bf16x2 v; unsigned u; } c0, c1, p0, p1;
              c0.u = cs2.x; c1.u = cs2.y;
              float v1a = A[rg] + bA.x, v2a = A[rg + 8] + bB.x;
              float v1b = A[rg + 1] + bA.y, v2b = A[rg + 9] + bB.y;
              if (qkv == 0) { v1a *= SCALE2; v2a *= SCALE2; v1b *= SCALE2; v2b *= SCALE2; }
              float ca = (float)c0.v[0], sa = (float)c0.v[1];
              float cb = (float)c1.v[0], sb = (float)c1.v[1];
              p0.v[0] = (__bf16)(v1a * ca + v2a * sa);
              p0.v[1] = (__bf16)(v2a * ca - v1a * sa);
              p1.v[0] = (__bf16)(v1b * cb + v2b * sb);
              p1.v[1] = (__bf16)(v2b * cb - v1b * sb);
              uint2 pkw; pkw.x = p0.u; pkw.y = p1.u;
              *(uint2*)&base[(h * 128 + l_me) * 40 + 2 * d0] = pkw;
            }
          }
        } else {  // v: write vT[h][d][l] XOR-swizzled
          if (live) {
#pragma unroll
            for (int rp = 0; rp < 8; ++rp) {
              const int rg = rp * 2;
              const int d0 = (rg & 3) + 8 * (rg >> 2) + 4 * hi;  // even, 0..30
              float2 bv = *(const float2*)&bb2L[nt * 32 + d0];
              float val0 = A[rg] + bv.x;
              float val1 = A[rg + 1] + bv.y;
              vT[(h * 32 + d0) * 128 + (l_me ^ ((d0 & 7) << 3))] = (__bf16)val0;
              vT[(h * 32 + d0 + 1) * 128 + (l_me ^ (((d0 + 1) & 7) << 3))] = (__bf16)val1;
            }
          }
        }
      }
    }
  }
  __syncthreads();  // QKV epilogue complete; tabL2 and bb2L dead from here on

  // ---- stage Wf2b -> ubuf and bfc2 -> bb2L (both dead regions); latency
  // hides under attention; consumed after the pre-FC2 barrier.
  {
    const uint4* wsrc = (const uint4*)Wf2b;
    uint4* wd = (uint4*)ubuf;
    wd[t] = wsrc[t];
    wd[512 + t] = wsrc[512 + t];
    wd[1024 + t] = wsrc[1024 + t];
    wd[1536 + t] = wsrc[1536 + t];
    if (t < 128) bb2L[t] = bfc2[t];  // bfc2L alias
  }

  // ======== attention: wave -> head (wv>>1); tasks qt = {wv&1, 3-(wv&1)} ====
  {
    const int h = wv >> 1;
    const int qtA = wv & 1, qtB = 3 - (wv & 1);
    // ---- preload BOTH tasks' q fragments; qs becomes yL after the barrier
    bf16x8 qf0A = *(const bf16x8*)&qs[(h * 128 + qtA * 32 + ln31) * 40 + hi * 8];
    bf16x8 qf1A = *(const bf16x8*)&qs[(h * 128 + qtA * 32 + ln31) * 40 + 16 + hi * 8];
    bf16x8 qf0B = *(const bf16x8*)&qs[(h * 128 + qtB * 32 + ln31) * 40 + hi * 8];
    bf16x8 qf1B = *(const bf16x8*)&qs[(h * 128 + qtB * 32 + ln31) * 40 + 16 + hi * 8];
    __syncthreads();  // all qs reads complete; alias qs storage as yL[128][136]
    __bf16* yL = qs;
#pragma unroll
    for (int ts = 0; ts < 2; ++ts) {
      const int qt = ts ? qtB : qtA;
      bf16x8 qf0 = ts ? qf0B : qf0A;  // static select (ts unrolled)
      bf16x8 qf1 = ts ? qf1B : qf1A;
      f32x16 s[4];
#pragma unroll
      for (int kt = 0; kt < 4; ++kt) {
        if (kt <= qt) {
          bf16x8 kf0 = *(const bf16x8*)&ksm[(h * 128 + kt * 32 + ln31) * 40 + hi * 8];
          bf16x8 kf1 = *(const bf16x8*)&ksm[(h * 128 + kt * 32 + ln31) * 40 + 16 + hi * 8];
          f32x16 z = {};
          z = __builtin_amdgcn_mfma_f32_32x32x16_bf16(kf0, qf0, z, 0, 0, 0);
          s[kt] = __builtin_amdgcn_mfma_f32_32x32x16_bf16(kf1, qf1, z, 0, 0, 0);
          if (kt == qt) {  // diagonal mask; s[] index compile-time (rule #20)
#pragma unroll
            for (int rg = 0; rg < 16; ++rg) {
              const int c_lo = (rg & 3) + 8 * (rg >> 2);
              int crow = c_lo + 4 * hi;
              s[kt][rg] = (crow <= ln31) ? s[kt][rg] : NEGINF;
            }
          }
        }
      }
      // softmax in log2 domain: in-lane + 1 shfl_xor(32) each for max and sum
      float mx = NEGINF;
#pragma unroll
      for (int kt = 0; kt < 4; ++kt)
        if (kt <= qt)
#pragma unroll
          for (int rg = 0; rg < 16; ++rg) mx = fmaxf(mx, s[kt][rg]);
      mx = fmaxf(mx, __shfl_xor(mx, 32));
      float sum = 0.0f;
#pragma unroll
      for (int kt = 0; kt < 4; ++kt)
        if (kt <= qt)
#pragma unroll
          for (int rg = 0; rg < 16; ++rg) {
            s[kt][rg] = exp2f(s[kt][rg] - mx);  // native v_exp_f32
            sum += s[kt][rg];
          }
      sum += __shfl_xor(sum, 32);
      float inv = 1.0f / sum;
      unsigned pk[4][8];
#pragma unroll
      for (int kt = 0; kt < 4; ++kt) {
        if (kt <= qt) {
#pragma unroll
          for (int p = 0; p < 8; ++p) {
            union { bf16x2 v; unsigned u; } w;
            w.v[0] = (__bf16)(s[kt][2 * p] * inv);
            w.v[1] = (__bf16)(s[kt][2 * p + 1] * inv);
            pk[kt][p] = w.u;
          }
        }
      }
      f32x16 o = {};
#pragma unroll
      for (int kt = 0; kt < 4; ++kt) {
        if (kt <= qt) {
#pragma unroll
          for (int m = 0; m < 2; ++m) {
            unsigned f0 = (unsigned)__shfl_xor((int)pk[kt][4 * m + 0], 32);
            unsigned f1 = (unsigned)__shfl_xor((int)pk[kt][4 * m + 1], 32);
            unsigned f2 = (unsigned)__shfl_xor((int)pk[kt][4 * m + 2], 32);
            unsigned f3 = (unsigned)__shfl_xor((int)pk[kt][4 * m + 3], 32);
            union { unsigned w[4]; bf16x8 v; } Aw;
            Aw.w[0] = hi ? f2 : pk[kt][4 * m + 0];
            Aw.w[1] = hi ? f3 : pk[kt][4 * m + 1];
            Aw.w[2] = hi ? pk[kt][4 * m + 2] : f0;
            Aw.w[3] = hi ? pk[kt][4 * m + 3] : f1;
            bf16x8 vf = *(const bf16x8*)&vT[(h * 32 + ln31) * 128 +
                ((kt * 32 + m * 16 + hi * 8) ^ ((ln31 & 7) << 3))];
            o = __builtin_amdgcn_mfma_f32_32x32x16_bf16(Aw.v, vf, o, 0, 0, 0);
          }
        }
      }
      // y -> yL (bf16, on-CU): row = query l, col = h*32 + d
#pragma unroll
      for (int rg = 0; rg < 16; ++rg) {
        const int c_lo = (rg & 3) + 8 * (rg >> 2);
        int l = qt * 32 + c_lo + 4 * hi;
        if (l < L_SEQ)
          yL[l * 136 + h * 32 + ln31] = (__bf16)o[rg];
      }
    }
  }

  // ======== FC2 + bias + SiLU: y, W, bias ALL from LDS ========
  __syncthreads();
  {
    const __bf16* Wf2bL = (const __bf16*)ubuf;
    const int ln15 = lane & 15, kg = lane >> 4;
    int yr = wv * 16 + ln15;
    if (yr > L_SEQ - 1) yr = L_SEQ - 1;
    bf16x8 af2[4];
#pragma unroll
    for (int kb = 0; kb < 4; ++kb)
      af2[kb] = *(const bf16x8*)&qs[yr * 136 + kb * 32 + kg * 8];  // yL alias
    float bc[8];
#pragma unroll
    for (int nt = 0; nt < 8; ++nt) bc[nt] = bb2L[nt * 16 + ln15];  // bfc2L
    f32x4 acc2[8] = {};
#pragma unroll
    for (int nt = 0; nt < 8; ++nt)
#pragma unroll
      for (int kb = 0; kb < 4; ++kb)
        acc2[nt] = __builtin_amdgcn_mfma_f32_16x16x32_bf16(
            af2[kb], *(const bf16x8*)&Wf2bL[(((nt * 4 + kb) * 64) + lane) * 8],
            acc2[nt], 0, 0, 0);
#pragma unroll
    for (int nt = 0; nt < 8; ++nt)
#pragma unroll
      for (int r = 0; r < 4; ++r) {
        int row = wv * 16 + kg * 4 + r, c = nt * 16 + ln15;
        if (row < L_SEQ) {
          float vv = acc2[nt][r] + bc[nt];
          out[((size_t)b * L_SEQ + row) * 128 + c] = vv / (1.0f + __expf(-vv));
        }
      }
  }
}

extern "C" void kernel_launch(void* const* d_in, const int* in_sizes, int n_in,
                              void* d_out, int out_size, void* d_ws,
                              size_t ws_size, hipStream_t stream) {
  const float* x = (const float*)d_in[0];
  const float* Wqkv = (const float*)d_in[1];
  const float* bqkv = (const float*)d_in[2];
  const float* Wfc2 = (const float*)d_in[3];
  const float* bfc2 = (const float*)d_in[4];
  float* out = (float*)d_out;

  char* ws = (char*)d_ws;
  unsigned* tab2 = (unsigned*)ws;                        // 30,464 B (pad 30,720)
  __bf16* Wb = (__bf16*)(ws + 30720);                    // 98,304 B
  float* bb2 = (float*)(ws + 30720 + 98304);             //  1,536 B
  __bf16* Wf2b = (__bf16*)(ws + 30720 + 98304 + 1536);   // 32,768 B (end 163,328)

  const int B = in_sizes[0] / (L_SEQ * D_MODEL);  // 2048
  prep_kernel<<<192, 256, 0, stream>>>(Wqkv, bqkv, Wfc2, tab2, Wb, bb2, Wf2b);
  fused_all<<<B, 512, 0, stream>>>(x, Wb, bb2, tab2, Wf2b, bfc2, out);
}